// Round 4
// baseline (2033.444 us; speedup 1.0000x reference)
//
#include <hip/hip_runtime.h>

// ---------------------------------------------------------------------------
// RPN head on gfx950: x --conv3x3(512->256)+relu--> h1 --conv3x3(256->256)+relu
//   --> h2 --1x1 heads (cls 18 / reg 36)--> softmax pairs --> out (B,H,W,9,6)
// R6: R4's register shape (8 waves, wave tile 128x64, acc[4][2] -- fits at
// VGPR~128, no spill) + R5's barrier schedule (2 barriers/TILE, not 6):
//   per BK=32 tile, 6 half-phases hp=(dx,ks); each hp:
//     { 6 ds_read_b128 (set hp+1, X/Y alternating) ; s_waitcnt lgkmcnt(6)
//       (waits only set hp) ; sched_barrier ; 8 MFMA on set hp }
//   -> in-wave read/MFMA overlap via counted waits; cross-wave overlap via
//   barrier removal (waves drift within the tile, LDS pipe + 4 matrix pipes
//   co-busy instead of R4's lockstep read-drain-then-MFMA-drain 2900 cyc).
//   Publish barrier (vmcnt(0), DMAs issued ~5 hp earlier) before hp5's
//   next-tile fragment load; tile-end WAR fence after hp5 (each wave's
//   lgkmcnt(6) at hp5 proves its buf-t reads retired).
// ---------------------------------------------------------------------------

typedef float f32x4  __attribute__((ext_vector_type(4)));
typedef float f32x16 __attribute__((ext_vector_type(16)));
typedef short bf16x8 __attribute__((ext_vector_type(8)));   // 8 bf16 = 4 VGPRs

union U16x8 { uint4 v; unsigned short s[8]; };

__device__ __forceinline__ unsigned short f2bf(float f) {
  union { float f; unsigned int u; } v; v.f = f;
  unsigned int r = v.u + 0x7FFFu + ((v.u >> 16) & 1u);   // RNE
  return (unsigned short)(r >> 16);
}

#define GLOAD_LDS16(G, L)                                        \
  __builtin_amdgcn_global_load_lds(                              \
      (const __attribute__((address_space(1))) void*)(G),        \
      (__attribute__((address_space(3))) void*)(L), 16, 0, 0)

// ---- transpose + fp32->bf16: src[z][K][N] -> dst[z][N][K] ------------------
__global__ __launch_bounds__(256) void transpose_cvt(
    const float* __restrict__ src, unsigned short* __restrict__ dst,
    int K, int N) {
  __shared__ float t[32][33];
  const int tx = threadIdx.x, ty = threadIdx.y;     // 32 x 8
  const int k0 = blockIdx.x * 32, n0 = blockIdx.y * 32;
  const float* s = src + (size_t)blockIdx.z * K * N;
  unsigned short* d = dst + (size_t)blockIdx.z * N * K;
#pragma unroll
  for (int r = 0; r < 32; r += 8) {
    int k = k0 + ty + r, n = n0 + tx;
    t[ty + r][tx] = (k < K && n < N) ? s[(size_t)k * N + n] : 0.f;
  }
  __syncthreads();
#pragma unroll
  for (int r = 0; r < 32; r += 8) {
    int n = n0 + ty + r, k = k0 + tx;
    if (n < N && k < K) d[(size_t)n * K + k] = f2bf(t[tx][ty + r]);
  }
}

// ---- x (f32 NHWC) -> x_pad (bf16, [4][130][130][512], zero halo) -----------
__global__ __launch_bounds__(256) void convert_x(
    const float* __restrict__ x, unsigned short* __restrict__ xp) {
  int idx = blockIdx.x * 256 + threadIdx.x;       // 4*130*130*64 exactly
  int g = idx & 63;                                // 8-channel group
  int cell = idx >> 6;
  int xpix = cell % 130;
  int t = cell / 130;
  int ypix = t % 130;
  int b = t / 130;
  U16x8 u;
  if (xpix == 0 || xpix == 129 || ypix == 0 || ypix == 129) {
    u.v = make_uint4(0u, 0u, 0u, 0u);
  } else {
    const float* sp = x + ((size_t)((b * 128 + ypix - 1) * 128) + (xpix - 1)) * 512 + g * 8;
    float4 a = *(const float4*)sp;
    float4 c = *(const float4*)(sp + 4);
    u.s[0] = f2bf(a.x); u.s[1] = f2bf(a.y); u.s[2] = f2bf(a.z); u.s[3] = f2bf(a.w);
    u.s[4] = f2bf(c.x); u.s[5] = f2bf(c.y); u.s[6] = f2bf(c.z); u.s[7] = f2bf(c.w);
  }
  *(uint4*)(xp + (size_t)cell * 512 + g * 8) = u.v;
}

// ---- zero the halo of h1_pad ([4][130][130][256]) --------------------------
__global__ __launch_bounds__(256) void zero_h1_borders(unsigned short* __restrict__ h1p) {
  int idx = blockIdx.x * 256 + threadIdx.x;       // 4*130*130*32 exactly
  int g = idx & 31;
  int cell = idx >> 5;
  int xpix = cell % 130;
  int t = cell / 130;
  int ypix = t % 130;
  if (xpix == 0 || xpix == 129 || ypix == 0 || ypix == 129)
    *(uint4*)(h1p + (size_t)cell * 256 + g * 8) = make_uint4(0u, 0u, 0u, 0u);
}

// ---- 3x3 conv, drift-scheduled implicit GEMM, bf16 MFMA 32x32x16 -----------
// Ap:  [4][130][130][CIN] bf16 (zero halo).  WT: [9][256][CIN] bf16 (B^T).
// Block tile: 256 px (2 rows x 128) x 256 cout; 8 waves 2Mx4N, wave 128x64,
// acc[4][2].  K-loop: tile t = (dy, ci0), BK=32; 6 half-phases per tile.
// LDS/buffer: A [2 rows][192 px][4 seg16] 24.6 KB + B [3][256][4 seg16]
// 49.2 KB, double-buffered = 147 456 B.  Stage = 9 global_load_lds(16B)/wave.
// Swizzle (both-sides): LDS slot = global seg ^ ((row>>1)&3).
template<int CIN, int MODE>
__global__ __launch_bounds__(512, 2) void conv3x3(
    const unsigned short* __restrict__ Ap,
    const unsigned short* __restrict__ WT,
    const float* __restrict__ bias,
    unsigned short* __restrict__ out) {
  constexpr int NCI    = CIN / 32;
  constexpr int LOGNCI = (NCI == 16) ? 4 : 3;
  constexpr int NT     = 3 * NCI;
  constexpr int A_BYTES = 2 * 192 * 4 * 16;       // 24 576
  constexpr int B_BYTES = 3 * 256 * 4 * 16;       // 49 152
  constexpr int BUF     = A_BYTES + B_BYTES;      // 73 728
  __shared__ __align__(16) unsigned char smem[2 * BUF];

  const int tid  = threadIdx.x;
  const int wave = tid >> 6, lane = tid & 63;
  const int l31 = lane & 31, hi = lane >> 5;
  const int wm = wave >> 2, wn = wave & 3;        // 2M x 4N wave grid
  const int b = blockIdx.x >> 6;
  const int y0 = (blockIdx.x & 63) * 2;
  const int brow = b * 130 + y0;                  // input row at dy=0

  // ---- per-thread staging decode (constant across iterations) -------------
  int a_go[3], a_ld[3];
#pragma unroll
  for (int i = 0; i < 3; ++i) {
    int s = (wave * 3 + i) * 64 + lane;           // 0..1535 (16B chunks of A)
    int rw = (s >= 768) ? 1 : 0;
    int r = s - rw * 768;
    int px = r >> 2, sl = r & 3;
    a_go[i] = (rw * 130 + px) * CIN + ((sl ^ ((px >> 1) & 3)) * 8);
    a_ld[i] = (wave * 3 + i) * 1024;
  }
  int b_go[6], b_ld[6];
#pragma unroll
  for (int i = 0; i < 6; ++i) {
    int s = (wave * 6 + i) * 64 + lane;           // 0..3071 (16B chunks of B)
    int dxs = s >> 10, r = s & 1023;
    int co = r >> 2, sl = r & 3;
    b_go[i] = (dxs * 256 + co) * CIN + ((sl ^ ((co >> 1) & 3)) * 8);
    b_ld[i] = A_BYTES + (wave * 6 + i) * 1024;
  }

  // bias loads issued (and retired) before the pipeline's vmcnt counting
  const float bb0 = bias[wn * 64 + l31];
  const float bb1 = bias[wn * 64 + 32 + l31];

  f32x16 acc[4][2] = {};
  const int bswz = (l31 >> 1) & 3;

  auto stage = [&](int tile) {
    const int dy  = tile >> LOGNCI;
    const int ci0 = (tile & (NCI - 1)) << 5;
    unsigned char* sb = smem + (size_t)(tile & 1) * BUF;
    const unsigned short* Ab = Ap + (size_t)(brow + dy) * 130 * CIN + ci0;
#pragma unroll
    for (int i = 0; i < 3; ++i)
      GLOAD_LDS16(Ab + a_go[i], sb + a_ld[i]);
    const unsigned short* Bb = WT + (size_t)dy * 3 * 256 * CIN + ci0;
#pragma unroll
    for (int i = 0; i < 6; ++i)
      GLOAD_LDS16(Bb + b_go[i], sb + b_ld[i]);
  };

  // fragment double-buffer (all statically named: no scratch, rule #20)
  bf16x8 Xa0, Xa1, Xa2, Xa3, Xb0, Xb1;
  bf16x8 Ya0, Ya1, Ya2, Ya3, Yb0, Yb1;

#define LOAD_FRAGS(SB, P, DX, KS) do {                                        \
    const unsigned char* sb_ = (SB);                                          \
    const int q_  = (KS) * 2 + hi;                                            \
    const int ab_ = wm * 12288 + (l31 + (DX)) * 64 +                          \
                    ((q_ ^ (((l31 + (DX)) >> 1) & 3)) * 16);                  \
    P##a0 = *(const bf16x8*)(sb_ + ab_);                                      \
    P##a1 = *(const bf16x8*)(sb_ + ab_ + 2048);                               \
    P##a2 = *(const bf16x8*)(sb_ + ab_ + 4096);                               \
    P##a3 = *(const bf16x8*)(sb_ + ab_ + 6144);                               \
    const int bb_ = A_BYTES + (DX) * 16384 + wn * 4096 + l31 * 64 +           \
                    ((q_ ^ bswz) * 16);                                       \
    P##b0 = *(const bf16x8*)(sb_ + bb_);                                      \
    P##b1 = *(const bf16x8*)(sb_ + bb_ + 2048);                               \
  } while (0)

#define MFMA_SET(P) do {                                                      \
    acc[0][0] = __builtin_amdgcn_mfma_f32_32x32x16_bf16(P##a0, P##b0, acc[0][0], 0, 0, 0); \
    acc[1][0] = __builtin_amdgcn_mfma_f32_32x32x16_bf16(P##a1, P##b0, acc[1][0], 0, 0, 0); \
    acc[2][0] = __builtin_amdgcn_mfma_f32_32x32x16_bf16(P##a2, P##b0, acc[2][0], 0, 0, 0); \
    acc[3][0] = __builtin_amdgcn_mfma_f32_32x32x16_bf16(P##a3, P##b0, acc[3][0], 0, 0, 0); \
    acc[0][1] = __builtin_amdgcn_mfma_f32_32x32x16_bf16(P##a0, P##b1, acc[0][1], 0, 0, 0); \
    acc[1][1] = __builtin_amdgcn_mfma_f32_32x32x16_bf16(P##a1, P##b1, acc[1][1], 0, 0, 0); \
    acc[2][1] = __builtin_amdgcn_mfma_f32_32x32x16_bf16(P##a2, P##b1, acc[2][1], 0, 0, 0); \
    acc[3][1] = __builtin_amdgcn_mfma_f32_32x32x16_bf16(P##a3, P##b1, acc[3][1], 0, 0, 0); \
  } while (0)

#define W6 do { asm volatile("s_waitcnt lgkmcnt(6)" ::: "memory");            \
                __builtin_amdgcn_sched_barrier(0); } while (0)
#define W0 do { asm volatile("s_waitcnt lgkmcnt(0)" ::: "memory");            \
                __builtin_amdgcn_sched_barrier(0); } while (0)

  // prologue: stage tile 0, publish, preload hp0 fragment set
  stage(0);
  asm volatile("s_waitcnt vmcnt(0)" ::: "memory");
  __builtin_amdgcn_s_barrier();
  __builtin_amdgcn_sched_barrier(0);
  LOAD_FRAGS(smem, Y, 0, 0);

#pragma unroll 1
  for (int t = 0; t < NT; ++t) {
    const unsigned char* sb  = smem + (size_t)(t & 1) * BUF;
    const unsigned char* sbn = smem + (size_t)((t + 1) & 1) * BUF;
    if (t + 1 < NT) stage(t + 1);                // 9 DMAs -> buf^1 (async)
    LOAD_FRAGS(sb, X, 0, 1); W6; MFMA_SET(Y);    // hp0
    LOAD_FRAGS(sb, Y, 1, 0); W6; MFMA_SET(X);    // hp1
    LOAD_FRAGS(sb, X, 1, 1); W6; MFMA_SET(Y);    // hp2
    LOAD_FRAGS(sb, Y, 2, 0); W6; MFMA_SET(X);    // hp3
    LOAD_FRAGS(sb, X, 2, 1); W6; MFMA_SET(Y);    // hp4
    __builtin_amdgcn_sched_barrier(0);
    asm volatile("s_waitcnt vmcnt(0)" ::: "memory");  // DMAs issued ~5 hp ago
    __builtin_amdgcn_s_barrier();                // publish buf t+1
    __builtin_amdgcn_sched_barrier(0);
    if (t + 1 < NT) {
      LOAD_FRAGS(sbn, Y, 0, 0); W6; MFMA_SET(X); // hp5: prefetch next hp0
    } else {
      W0; MFMA_SET(X);                           // last tile: just finish
    }
    __builtin_amdgcn_sched_barrier(0);
    __builtin_amdgcn_s_barrier();                // tile-end WAR fence
    __builtin_amdgcn_sched_barrier(0);
  }

#undef LOAD_FRAGS
#undef MFMA_SET
#undef W6
#undef W0

  // epilogue: 32x32 C/D layout: col = lane&31, row = (reg&3)+8*(reg>>2)+4*hi
#pragma unroll
  for (int i = 0; i < 4; ++i) {
#pragma unroll
    for (int j = 0; j < 2; ++j) {
      const int n = wn * 64 + j * 32 + l31;
      const float bb = j ? bb1 : bb0;
#pragma unroll
      for (int reg = 0; reg < 16; ++reg) {
        int px = i * 32 + (reg & 3) + 8 * (reg >> 2) + 4 * hi;
        float v = fmaxf(acc[i][j][reg] + bb, 0.f);
        size_t off;
        if (MODE == 0)
          off = ((size_t)(brow + wm + 1) * 130 + (px + 1)) * 256 + n;
        else
          off = ((size_t)((b * 128 + y0 + wm) * 128) + px) * 256 + n;
        out[off] = f2bf(v);
      }
    }
  }
}

// ---- heads: h2[65536][256] x WhT[54(pad 64)][256] + bias, softmax pairs ----
__global__ __launch_bounds__(256) void heads_kernel(
    const unsigned short* __restrict__ h2,
    const unsigned short* __restrict__ WhT,
    const float* __restrict__ br, const float* __restrict__ bc,
    float* __restrict__ out) {
  __shared__ __align__(16) unsigned short As[64][264];
  const int tid = threadIdx.x;
  const int wave = tid >> 6, lane = tid & 63;
  const int quad = lane >> 4, l16 = lane & 15;
  const int pix0 = blockIdx.x * 64;
#pragma unroll
  for (int r = 0; r < 8; ++r) {
    int s = r * 256 + tid;
    int row = s >> 5, seg = s & 31;                  // 64 rows x 32 x 16B
    *(uint4*)&As[row][seg * 8] =
        *(const uint4*)(h2 + (size_t)(pix0 + row) * 256 + seg * 8);
  }
  __syncthreads();
  f32x4 acc[4] = {};
#pragma unroll
  for (int ks = 0; ks < 8; ++ks) {
    bf16x8 af = *(const bf16x8*)&As[wave * 16 + l16][ks * 32 + quad * 8];
#pragma unroll
    for (int j = 0; j < 4; ++j) {
      bf16x8 bfr = *(const bf16x8*)(WhT + (size_t)(j * 16 + l16) * 256 + ks * 32 + quad * 8);
      acc[j] = __builtin_amdgcn_mfma_f32_16x16x32_bf16(af, bfr, acc[j], 0, 0, 0);
    }
  }
#pragma unroll
  for (int j = 0; j < 4; ++j) {
    int n = j * 16 + l16;                            // head channel (cls 0-17, reg 18-53)
    float bias = 0.f;
    if (n < 18) bias = bc[n];
    else if (n < 54) bias = br[n - 18];
#pragma unroll
    for (int r = 0; r < 4; ++r) {
      int p = pix0 + wave * 16 + quad * 4 + r;       // pixel
      float v = acc[j][r] + bias;
      float partner = __shfl_xor(v, 1);              // cls pair (even,odd lanes)
      if (n < 18) {
        float mx = fmaxf(v, partner);
        float e0 = __expf(v - mx), e1 = __expf(partner - mx);
        int a = n >> 1, sl = n & 1;
        out[(size_t)p * 54 + a * 6 + sl] = e0 / (e0 + e1);
      } else if (n < 54) {
        int rr = n - 18, a = rr >> 2, sl = (rr & 3) + 2;
        out[(size_t)p * 54 + a * 6 + sl] = v;
      }
    }
  }
}

// ---------------------------------------------------------------------------
extern "C" void kernel_launch(void* const* d_in, const int* in_sizes, int n_in,
                              void* d_out, int out_size, void* d_ws, size_t ws_size,
                              hipStream_t stream) {
  const float* x  = (const float*)d_in[0];
  const float* W1 = (const float*)d_in[1];
  const float* b1 = (const float*)d_in[2];
  const float* W2 = (const float*)d_in[3];
  const float* b2 = (const float*)d_in[4];
  const float* Wr = (const float*)d_in[5];
  const float* br = (const float*)d_in[6];
  const float* Wc = (const float*)d_in[7];
  const float* bc = (const float*)d_in[8];
  float* out = (float*)d_out;

  // workspace carve-up (bytes).  NOTE: conv3x3 A-staging over-reads up to
  // ~64 KB past x_pad / ~32 KB past h1_pad (uniform-DMA row padding to 192 px);
  // those reads land in the NEXT buffer and are never consumed by MFMA, so no
  // extra padding is required as long as the order below is kept.
  constexpr size_t XPAD_B  = 4ull * 130 * 130 * 512 * 2;   //  69,222,400
  constexpr size_t H1PAD_B = 4ull * 130 * 130 * 256 * 2;   //  34,611,200
  constexpr size_t H2_B    = 4ull * 128 * 128 * 256 * 2;   //  33,554,432
  constexpr size_t W1T_B   = 9ull * 256 * 512 * 2;         //   2,359,296
  constexpr size_t W2T_B   = 9ull * 256 * 256 * 2;         //   1,179,648
  char* ws = (char*)d_ws;
  unsigned short* x_pad  = (unsigned short*)(ws);
  unsigned short* h1_pad = (unsigned short*)(ws + XPAD_B);
  unsigned short* h2     = (unsigned short*)(ws + XPAD_B + H1PAD_B);
  unsigned short* W1T    = (unsigned short*)(ws + XPAD_B + H1PAD_B + H2_B);
  unsigned short* W2T    = (unsigned short*)(ws + XPAD_B + H1PAD_B + H2_B + W1T_B);
  unsigned short* WhT    = (unsigned short*)(ws + XPAD_B + H1PAD_B + H2_B + W1T_B + W2T_B);

  // zero the padded head-weight block (rows 54..63 are read by MFMA)
  hipMemsetAsync(WhT, 0, 64ull * 256 * 2, stream);
  // weight repacks (B^T, bf16)
  transpose_cvt<<<dim3(16, 8, 9), dim3(32, 8), 0, stream>>>(W1, W1T, 512, 256);
  transpose_cvt<<<dim3(8, 8, 9),  dim3(32, 8), 0, stream>>>(W2, W2T, 256, 256);
  transpose_cvt<<<dim3(8, 1, 1),  dim3(32, 8), 0, stream>>>(Wc, WhT, 256, 18);
  transpose_cvt<<<dim3(8, 2, 1),  dim3(32, 8), 0, stream>>>(Wr, WhT + 18 * 256, 256, 36);
  // input pad+convert, h1 halo zero
  convert_x<<<16900, 256, 0, stream>>>(x, x_pad);
  zero_h1_borders<<<8450, 256, 0, stream>>>(h1_pad);
  // conv1: 512ci -> h1_pad (interior) ; conv2: 256ci -> h2 flat
  conv3x3<512, 0><<<256, 512, 0, stream>>>(x_pad, W1T, b1, h1_pad);
  conv3x3<256, 1><<<256, 512, 0, stream>>>(h1_pad, W2T, b2, h2);
  // 1x1 heads + softmax + interleave
  heads_kernel<<<1024, 256, 0, stream>>>(h2, WhT, br, bc, out);
}

// Round 6
// 551.882 us; speedup vs baseline: 3.6846x; 3.6846x over previous
//
#include <hip/hip_runtime.h>

// ---------------------------------------------------------------------------
// RPN head on gfx950: x --conv3x3(512->256)+relu--> h1 --conv3x3(256->256)+relu
//   --> h2 --1x1 heads (cls 18 / reg 36)--> softmax pairs --> out (B,H,W,9,6)
// R7 (resubmit; prior round was a container infra failure, no measurement)
// = R4 (verified 174 us conv1) + k-granule-major LDS layout.
//   R4's 64-B LDS rows made bank index depend only on row&1 -> every
//   ds_read_b128 was a structural 4-way conflict (SQ_LDS_BANK_CONFLICT
//   1.4e7 = +384 cyc/phase, ~2x the conflict-free LDS drain).  New layout:
//   A [imgrow*4+q][192 px][16B], B [dx*4+q][256 co][16B] -- a wave's 32-lane
//   fragment read is 512 CONTIGUOUS bytes = canonical conflict-free pattern.
//   Permutation applied on the global source at DMA time (LDS dest stays
//   linear, as global_load_lds requires); reader uses the same map.
//   Barrier schedule, register shape, staging counts: identical to R4.
// ---------------------------------------------------------------------------

typedef float f32x4  __attribute__((ext_vector_type(4)));
typedef float f32x16 __attribute__((ext_vector_type(16)));
typedef short bf16x8 __attribute__((ext_vector_type(8)));   // 8 bf16 = 4 VGPRs

union U16x8 { uint4 v; unsigned short s[8]; };

__device__ __forceinline__ unsigned short f2bf(float f) {
  union { float f; unsigned int u; } v; v.f = f;
  unsigned int r = v.u + 0x7FFFu + ((v.u >> 16) & 1u);   // RNE
  return (unsigned short)(r >> 16);
}

#define GLOAD_LDS16(G, L)                                        \
  __builtin_amdgcn_global_load_lds(                              \
      (const __attribute__((address_space(1))) void*)(G),        \
      (__attribute__((address_space(3))) void*)(L), 16, 0, 0)

// ---- transpose + fp32->bf16: src[z][K][N] -> dst[z][N][K] ------------------
__global__ __launch_bounds__(256) void transpose_cvt(
    const float* __restrict__ src, unsigned short* __restrict__ dst,
    int K, int N) {
  __shared__ float t[32][33];
  const int tx = threadIdx.x, ty = threadIdx.y;     // 32 x 8
  const int k0 = blockIdx.x * 32, n0 = blockIdx.y * 32;
  const float* s = src + (size_t)blockIdx.z * K * N;
  unsigned short* d = dst + (size_t)blockIdx.z * N * K;
#pragma unroll
  for (int r = 0; r < 32; r += 8) {
    int k = k0 + ty + r, n = n0 + tx;
    t[ty + r][tx] = (k < K && n < N) ? s[(size_t)k * N + n] : 0.f;
  }
  __syncthreads();
#pragma unroll
  for (int r = 0; r < 32; r += 8) {
    int n = n0 + ty + r, k = k0 + tx;
    if (n < N && k < K) d[(size_t)n * K + k] = f2bf(t[tx][ty + r]);
  }
}

// ---- x (f32 NHWC) -> x_pad (bf16, [4][130][130][512], zero halo) -----------
__global__ __launch_bounds__(256) void convert_x(
    const float* __restrict__ x, unsigned short* __restrict__ xp) {
  int idx = blockIdx.x * 256 + threadIdx.x;       // 4*130*130*64 exactly
  int g = idx & 63;                                // 8-channel group
  int cell = idx >> 6;
  int xpix = cell % 130;
  int t = cell / 130;
  int ypix = t % 130;
  int b = t / 130;
  U16x8 u;
  if (xpix == 0 || xpix == 129 || ypix == 0 || ypix == 129) {
    u.v = make_uint4(0u, 0u, 0u, 0u);
  } else {
    const float* sp = x + ((size_t)((b * 128 + ypix - 1) * 128) + (xpix - 1)) * 512 + g * 8;
    float4 a = *(const float4*)sp;
    float4 c = *(const float4*)(sp + 4);
    u.s[0] = f2bf(a.x); u.s[1] = f2bf(a.y); u.s[2] = f2bf(a.z); u.s[3] = f2bf(a.w);
    u.s[4] = f2bf(c.x); u.s[5] = f2bf(c.y); u.s[6] = f2bf(c.z); u.s[7] = f2bf(c.w);
  }
  *(uint4*)(xp + (size_t)cell * 512 + g * 8) = u.v;
}

// ---- zero the halo of h1_pad ([4][130][130][256]) --------------------------
__global__ __launch_bounds__(256) void zero_h1_borders(unsigned short* __restrict__ h1p) {
  int idx = blockIdx.x * 256 + threadIdx.x;       // 4*130*130*32 exactly
  int g = idx & 31;
  int cell = idx >> 5;
  int xpix = cell % 130;
  int t = cell / 130;
  int ypix = t % 130;
  if (xpix == 0 || xpix == 129 || ypix == 0 || ypix == 129)
    *(uint4*)(h1p + (size_t)cell * 256 + g * 8) = make_uint4(0u, 0u, 0u, 0u);
}

// ---- 3x3 conv, phase-split implicit GEMM, bf16 MFMA 32x32x16 ---------------
// Ap:  [4][130][130][CIN] bf16 (zero halo).  WT: [9][256][CIN] bf16 (B^T).
// Block tile: 256 px (2 rows x 128) x 256 cout; 8 waves 2Mx4N, wave 128x64,
// acc[4][2].  K-loop: tile t = (dy, ci0), BK=32; 3 phases (dx) per tile;
// per phase/wave: 12 ds_read_b128 + 16 MFMA, R4 barrier schedule:
//   { reads ; [dx0: stage t+1] ; [dx2: vmcnt(0)] ; s_barrier ; lgkmcnt(0) ;
//     setprio(1) ; 16 MFMA ; setprio(0) ; s_barrier }
// LDS (k-granule-major, conflict-free):
//   A: [rw*4+q][192 px][16B]  = 24 576 B   (q = 8-channel granule of BK=32)
//   B: [dx*4+q][256 co][16B]  = 49 152 B   double-buffered = 147 456 B
// Fragment read = 32 lanes x consecutive px/co at fixed q = 512 contiguous B.
template<int CIN, int MODE>
__global__ __launch_bounds__(512, 2) void conv3x3(
    const unsigned short* __restrict__ Ap,
    const unsigned short* __restrict__ WT,
    const float* __restrict__ bias,
    unsigned short* __restrict__ out) {
  constexpr int NCI    = CIN / 32;
  constexpr int LOGNCI = (NCI == 16) ? 4 : 3;
  constexpr int NT     = 3 * NCI;
  constexpr int A_BYTES = 8 * 192 * 16;           // 24 576
  constexpr int B_BYTES = 12 * 256 * 16;          // 49 152
  constexpr int BUF     = A_BYTES + B_BYTES;      // 73 728
  __shared__ __align__(16) unsigned char smem[2 * BUF];

  const int tid  = threadIdx.x;
  const int wave = tid >> 6, lane = tid & 63;
  const int l31 = lane & 31, hi = lane >> 5;
  const int wm = wave >> 2, wn = wave & 3;        // 2M x 4N wave grid
  const int b = blockIdx.x >> 6;
  const int y0 = (blockIdx.x & 63) * 2;
  const int brow = b * 130 + y0;                  // input row at dy=0

  // ---- per-thread staging decode (constant across iterations) -------------
  // A chunk c=0..1535 -> LDS byte c*16 = [(rw*4+q)*192+px]*16
  int a_go[3], a_ld[3];
#pragma unroll
  for (int i = 0; i < 3; ++i) {
    int c = (wave * 3 + i) * 64 + lane;
    int px = c % 192, t = c / 192;
    int q = t & 3, rw = t >> 2;
    a_go[i] = (rw * 130 + px) * CIN + q * 8;
    a_ld[i] = (wave * 3 + i) * 1024;
  }
  // B chunk c=0..3071 -> LDS byte A_BYTES + c*16 = [(dx*4+q)*256+co]*16
  int b_go[6], b_ld[6];
#pragma unroll
  for (int i = 0; i < 6; ++i) {
    int c = (wave * 6 + i) * 64 + lane;
    int co = c & 255, t = c >> 8;
    int q = t & 3, dxs = t >> 2;
    b_go[i] = (dxs * 256 + co) * CIN + q * 8;
    b_ld[i] = A_BYTES + (wave * 6 + i) * 1024;
  }

  // bias loads issued (and retired) before the pipeline's vmcnt counting
  const float bb0 = bias[wn * 64 + l31];
  const float bb1 = bias[wn * 64 + 32 + l31];

  f32x16 acc[4][2] = {};

  auto stage = [&](int tile) {
    const int dy  = tile >> LOGNCI;
    const int ci0 = (tile & (NCI - 1)) << 5;
    unsigned char* sb = smem + (size_t)(tile & 1) * BUF;
    const unsigned short* Ab = Ap + (size_t)(brow + dy) * 130 * CIN + ci0;
#pragma unroll
    for (int i = 0; i < 3; ++i)
      GLOAD_LDS16(Ab + a_go[i], sb + a_ld[i]);
    const unsigned short* Bb = WT + (size_t)dy * 3 * 256 * CIN + ci0;
#pragma unroll
    for (int i = 0; i < 6; ++i)
      GLOAD_LDS16(Bb + b_go[i], sb + b_ld[i]);
  };

  // prologue: stage tile 0, publish
  stage(0);
  asm volatile("s_waitcnt vmcnt(0)" ::: "memory");
  __builtin_amdgcn_s_barrier();

#pragma unroll 2
  for (int t = 0; t < NT; ++t) {
    const unsigned char* sb = smem + (size_t)(t & 1) * BUF;
#pragma unroll
    for (int dx = 0; dx < 3; ++dx) {
      // ---- this phase's fragment reads (buf t; conflict-free contiguous) --
      bf16x8 af[2][4], bfr[2][2];
#pragma unroll
      for (int ks = 0; ks < 2; ++ks) {
        const int q_ = ks * 2 + hi;
        const int ab = ((wm * 4 + q_) * 192 + dx + l31) * 16;
        const int bb = A_BYTES + ((dx * 4 + q_) * 256 + wn * 64 + l31) * 16;
#pragma unroll
        for (int i = 0; i < 4; ++i)
          af[ks][i] = *(const bf16x8*)(sb + ab + i * 512);
#pragma unroll
        for (int j = 0; j < 2; ++j)
          bfr[ks][j] = *(const bf16x8*)(sb + bb + j * 512);
      }
      // ---- staging schedule for tile t+1 ----------------------------------
      if (dx == 0 && t + 1 < NT) stage(t + 1);     // 9 DMAs -> buf^1 (WAR-safe)
      if (dx == 2 && t + 1 < NT)                   // issued 2 phases ago: no stall
        asm volatile("s_waitcnt vmcnt(0)" ::: "memory");
      __builtin_amdgcn_sched_barrier(0);
      __builtin_amdgcn_s_barrier();                // (t,2): publishes buf t+1
      asm volatile("s_waitcnt lgkmcnt(0)" ::: "memory");
      __builtin_amdgcn_sched_barrier(0);
      __builtin_amdgcn_s_setprio(1);
#pragma unroll
      for (int ks = 0; ks < 2; ++ks)
#pragma unroll
        for (int i = 0; i < 4; ++i)
#pragma unroll
          for (int j = 0; j < 2; ++j)
            acc[i][j] = __builtin_amdgcn_mfma_f32_32x32x16_bf16(
                af[ks][i], bfr[ks][j], acc[i][j], 0, 0, 0);
      __builtin_amdgcn_s_setprio(0);
      __builtin_amdgcn_sched_barrier(0);
      __builtin_amdgcn_s_barrier();                // phase close
    }
  }

  // epilogue: 32x32 C/D layout: col = lane&31, row = (reg&3)+8*(reg>>2)+4*hi
#pragma unroll
  for (int i = 0; i < 4; ++i) {
#pragma unroll
    for (int j = 0; j < 2; ++j) {
      const int n = wn * 64 + j * 32 + l31;
      const float bb = j ? bb1 : bb0;
#pragma unroll
      for (int reg = 0; reg < 16; ++reg) {
        int px = i * 32 + (reg & 3) + 8 * (reg >> 2) + 4 * hi;
        float v = fmaxf(acc[i][j][reg] + bb, 0.f);
        size_t off;
        if (MODE == 0)
          off = ((size_t)(brow + wm + 1) * 130 + (px + 1)) * 256 + n;
        else
          off = ((size_t)((b * 128 + y0 + wm) * 128) + px) * 256 + n;
        out[off] = f2bf(v);
      }
    }
  }
}

// ---- heads: h2[65536][256] x WhT[54(pad 64)][256] + bias, softmax pairs ----
__global__ __launch_bounds__(256) void heads_kernel(
    const unsigned short* __restrict__ h2,
    const unsigned short* __restrict__ WhT,
    const float* __restrict__ br, const float* __restrict__ bc,
    float* __restrict__ out) {
  __shared__ __align__(16) unsigned short As[64][264];
  const int tid = threadIdx.x;
  const int wave = tid >> 6, lane = tid & 63;
  const int quad = lane >> 4, l16 = lane & 15;
  const int pix0 = blockIdx.x * 64;
#pragma unroll
  for (int r = 0; r < 8; ++r) {
    int s = r * 256 + tid;
    int row = s >> 5, seg = s & 31;                  // 64 rows x 32 x 16B
    *(uint4*)&As[row][seg * 8] =
        *(const uint4*)(h2 + (size_t)(pix0 + row) * 256 + seg * 8);
  }
  __syncthreads();
  f32x4 acc[4] = {};
#pragma unroll
  for (int ks = 0; ks < 8; ++ks) {
    bf16x8 af = *(const bf16x8*)&As[wave * 16 + l16][ks * 32 + quad * 8];
#pragma unroll
    for (int j = 0; j < 4; ++j) {
      bf16x8 bfr = *(const bf16x8*)(WhT + (size_t)(j * 16 + l16) * 256 + ks * 32 + quad * 8);
      acc[j] = __builtin_amdgcn_mfma_f32_16x16x32_bf16(af, bfr, acc[j], 0, 0, 0);
    }
  }
#pragma unroll
  for (int j = 0; j < 4; ++j) {
    int n = j * 16 + l16;                            // head channel (cls 0-17, reg 18-53)
    float bias = 0.f;
    if (n < 18) bias = bc[n];
    else if (n < 54) bias = br[n - 18];
#pragma unroll
    for (int r = 0; r < 4; ++r) {
      int p = pix0 + wave * 16 + quad * 4 + r;       // pixel
      float v = acc[j][r] + bias;
      float partner = __shfl_xor(v, 1);              // cls pair (even,odd lanes)
      if (n < 18) {
        float mx = fmaxf(v, partner);
        float e0 = __expf(v - mx), e1 = __expf(partner - mx);
        int a = n >> 1, sl = n & 1;
        out[(size_t)p * 54 + a * 6 + sl] = e0 / (e0 + e1);
      } else if (n < 54) {
        int rr = n - 18, a = rr >> 2, sl = (rr & 3) + 2;
        out[(size_t)p * 54 + a * 6 + sl] = v;
      }
    }
  }
}

// ---------------------------------------------------------------------------
extern "C" void kernel_launch(void* const* d_in, const int* in_sizes, int n_in,
                              void* d_out, int out_size, void* d_ws, size_t ws_size,
                              hipStream_t stream) {
  const float* x  = (const float*)d_in[0];
  const float* W1 = (const float*)d_in[1];
  const float* b1 = (const float*)d_in[2];
  const float* W2 = (const float*)d_in[3];
  const float* b2 = (const float*)d_in[4];
  const float* Wr = (const float*)d_in[5];
  const float* br = (const float*)d_in[6];
  const float* Wc = (const float*)d_in[7];
  const float* bc = (const float*)d_in[8];
  float* out = (float*)d_out;

  // workspace carve-up (bytes).  NOTE: conv3x3 A-staging over-reads up to
  // ~64 KB past x_pad / ~32 KB past h1_pad (uniform-DMA row padding to 192 px);
  // those reads land in the NEXT buffer and are never consumed by MFMA, so no
  // extra padding is required as long as the order below is kept.
  constexpr size_t XPAD_B  = 4ull * 130 * 130 * 512 * 2;   //  69,222,400
  constexpr size_t H1PAD_B = 4ull * 130 * 130 * 256 * 2;   //  34,611,200
  constexpr size_t H2_B    = 4ull * 128 * 128 * 256 * 2;   //  33,554,432
  constexpr size_t W1T_B   = 9ull * 256 * 512 * 2;         //   2,359,296
  constexpr size_t W2T_B   = 9ull * 256 * 256 * 2;         //   1,179,648
  char* ws = (char*)d_ws;
  unsigned short* x_pad  = (unsigned short*)(ws);
  unsigned short* h1_pad = (unsigned short*)(ws + XPAD_B);
  unsigned short* h2     = (unsigned short*)(ws + XPAD_B + H1PAD_B);
  unsigned short* W1T    = (unsigned short*)(ws + XPAD_B + H1PAD_B + H2_B);
  unsigned short* W2T    = (unsigned short*)(ws + XPAD_B + H1PAD_B + H2_B + W1T_B);
  unsigned short* WhT    = (unsigned short*)(ws + XPAD_B + H1PAD_B + H2_B + W1T_B + W2T_B);

  // zero the padded head-weight block (rows 54..63 are read by MFMA)
  hipMemsetAsync(WhT, 0, 64ull * 256 * 2, stream);
  // weight repacks (B^T, bf16)
  transpose_cvt<<<dim3(16, 8, 9), dim3(32, 8), 0, stream>>>(W1, W1T, 512, 256);
  transpose_cvt<<<dim3(8, 8, 9),  dim3(32, 8), 0, stream>>>(W2, W2T, 256, 256);
  transpose_cvt<<<dim3(8, 1, 1),  dim3(32, 8), 0, stream>>>(Wc, WhT, 256, 18);
  transpose_cvt<<<dim3(8, 2, 1),  dim3(32, 8), 0, stream>>>(Wr, WhT + 18 * 256, 256, 36);
  // input pad+convert, h1 halo zero
  convert_x<<<16900, 256, 0, stream>>>(x, x_pad);
  zero_h1_borders<<<8450, 256, 0, stream>>>(h1_pad);
  // conv1: 512ci -> h1_pad (interior) ; conv2: 256ci -> h2 flat
  conv3x3<512, 0><<<256, 512, 0, stream>>>(x_pad, W1T, b1, h1_pad);
  conv3x3<256, 1><<<256, 512, 0, stream>>>(h1_pad, W2T, b2, h2);
  // 1x1 heads + softmax + interleave
  heads_kernel<<<1024, 256, 0, stream>>>(h2, WhT, br, bc, out);
}

// Round 7
// 461.989 us; speedup vs baseline: 4.4015x; 1.1946x over previous
//
#include <hip/hip_runtime.h>

// ---------------------------------------------------------------------------
// RPN head on gfx950: x --conv3x3(512->256)+relu--> h1 --conv3x3(256->256)+relu
//   --> h2 --1x1 heads (cls 18 / reg 36)--> softmax pairs --> out (B,H,W,9,6)
// R8 = R7's conflict-free k-granule-major LDS (verified: SQ_LDS_BANK_CONFLICT
// 1.4e7 -> 0) + producer-side global repacking to restore DMA coalescing
// (R7's regression: q-major chunk order made each lane's 16B hit its own
// cache line -> 4x L2 transactions per global_load_lds):
//   - weights pre-packed by pack_w into exact per-tile LDS order
//     [dy*NCI+kt][(dx*4+q)*256+co][8] -> staging source PERFECTLY linear
//   - activations stored granule-major [b][y][ci/8][px][8] by convert_x /
//     conv1 epilogue -> each A q-row is a 2176-B contiguous run
// Schedule, wave shape (8 waves, acc[4][2], ~124 VGPR), barriers: R4/R7.
// ---------------------------------------------------------------------------

typedef float f32x4  __attribute__((ext_vector_type(4)));
typedef float f32x16 __attribute__((ext_vector_type(16)));
typedef short bf16x8 __attribute__((ext_vector_type(8)));   // 8 bf16 = 4 VGPRs

union U16x8 { uint4 v; unsigned short s[8]; };

__device__ __forceinline__ unsigned short f2bf(float f) {
  union { float f; unsigned int u; } v; v.f = f;
  unsigned int r = v.u + 0x7FFFu + ((v.u >> 16) & 1u);   // RNE
  return (unsigned short)(r >> 16);
}

#define GLOAD_LDS16(G, L)                                        \
  __builtin_amdgcn_global_load_lds(                              \
      (const __attribute__((address_space(1))) void*)(G),        \
      (__attribute__((address_space(3))) void*)(L), 16, 0, 0)

// ---- transpose + fp32->bf16: src[z][K][N] -> dst[z][N][K] (heads only) -----
__global__ __launch_bounds__(256) void transpose_cvt(
    const float* __restrict__ src, unsigned short* __restrict__ dst,
    int K, int N) {
  __shared__ float t[32][33];
  const int tx = threadIdx.x, ty = threadIdx.y;     // 32 x 8
  const int k0 = blockIdx.x * 32, n0 = blockIdx.y * 32;
  const float* s = src + (size_t)blockIdx.z * K * N;
  unsigned short* d = dst + (size_t)blockIdx.z * N * K;
#pragma unroll
  for (int r = 0; r < 32; r += 8) {
    int k = k0 + ty + r, n = n0 + tx;
    t[ty + r][tx] = (k < K && n < N) ? s[(size_t)k * N + n] : 0.f;
  }
  __syncthreads();
#pragma unroll
  for (int r = 0; r < 32; r += 8) {
    int n = n0 + ty + r, k = k0 + tx;
    if (n < N && k < K) d[(size_t)n * K + k] = f2bf(t[tx][ty + r]);
  }
}

// ---- pack conv weights (3,3,CIN,256) f32 -> per-tile LDS order bf16 --------
// out[(dy*NCI+kt)*24576 + ((dx*4+q)*256+co)*8 + e] = W[dy][dx][kt*32+q*8+e][co]
__global__ __launch_bounds__(256) void pack_w(
    const float* __restrict__ W, unsigned short* __restrict__ out, int CIN) {
  const int NCI = CIN / 32;
  int tid = blockIdx.x * 256 + threadIdx.x;        // 9*NCI*1024 total
  int co = tid & 255;
  int q  = (tid >> 8) & 3;
  int t  = tid >> 10;
  int dx = t % 3;
  int r  = t / 3;
  int kt = r % NCI;
  int dy = r / NCI;
  U16x8 u;
#pragma unroll
  for (int e = 0; e < 8; ++e) {
    int ci = kt * 32 + q * 8 + e;
    u.s[e] = f2bf(W[((size_t)(dy * 3 + dx) * CIN + ci) * 256 + co]);
  }
  *(uint4*)(out + (size_t)tid * 8) = u.v;
}

// ---- x (f32 NHWC) -> x_pad (bf16 granule-major [4][130][64][130][8]) -------
__global__ __launch_bounds__(256) void convert_x(
    const float* __restrict__ x, unsigned short* __restrict__ xp) {
  int idx = blockIdx.x * 256 + threadIdx.x;       // 4*130*130*64 exactly
  int g = idx & 63;                                // 8-channel granule
  int cell = idx >> 6;
  int xpix = cell % 130;
  int t = cell / 130;
  int ypix = t % 130;
  int b = t / 130;
  U16x8 u;
  if (xpix == 0 || xpix == 129 || ypix == 0 || ypix == 129) {
    u.v = make_uint4(0u, 0u, 0u, 0u);
  } else {
    const float* sp = x + ((size_t)((b * 128 + ypix - 1) * 128) + (xpix - 1)) * 512 + g * 8;
    float4 a = *(const float4*)sp;
    float4 c = *(const float4*)(sp + 4);
    u.s[0] = f2bf(a.x); u.s[1] = f2bf(a.y); u.s[2] = f2bf(a.z); u.s[3] = f2bf(a.w);
    u.s[4] = f2bf(c.x); u.s[5] = f2bf(c.y); u.s[6] = f2bf(c.z); u.s[7] = f2bf(c.w);
  }
  *(uint4*)(xp + (((size_t)(b * 130 + ypix) * 64 + g) * 130 + xpix) * 8) = u.v;
}

// ---- zero the halo of h1_pad (granule-major [4][130][32][130][8]) ----------
__global__ __launch_bounds__(256) void zero_h1_borders(unsigned short* __restrict__ h1p) {
  int idx = blockIdx.x * 256 + threadIdx.x;       // 4*130*32*130 exactly
  int px = idx % 130;
  int t = idx / 130;
  int g = t & 31;
  int tt = t >> 5;
  int y = tt % 130;
  int b = tt / 130;
  if (px == 0 || px == 129 || y == 0 || y == 129)
    *(uint4*)(h1p + (((size_t)(b * 130 + y) * 32 + g) * 130 + px) * 8) =
        make_uint4(0u, 0u, 0u, 0u);
}

// ---- 3x3 conv, phase-split implicit GEMM, bf16 MFMA 32x32x16 ---------------
// Ap:  granule-major [4][130][CIN/8][130][8] bf16 (zero halo).
// WTp: packed [3*NCI blocks][(dx*4+q)*256+co][8] bf16.
// Block tile: 256 px (2 rows x 128) x 256 cout; 8 waves 2Mx4N, wave 128x64,
// acc[4][2].  K-loop: tile t = (dy, kt), BK=32; 3 phases (dx) per tile;
// per phase/wave: 12 ds_read_b128 + 16 MFMA, R4 barrier schedule.
// LDS (k-granule-major, conflict-free; R7-verified 0 conflicts):
//   A: [rw*4+q][136 px][16B] = 17 408 B ; B: [dx*4+q][256 co][16B] = 49 152 B
//   double-buffered BUF=66 560 -> 133 120 B total.
// Staging: B source = base + chunk*16 (linear); A source = 2176-B runs.
template<int CIN, int MODE>
__global__ __launch_bounds__(512, 2) void conv3x3(
    const unsigned short* __restrict__ Ap,
    const unsigned short* __restrict__ WTp,
    const float* __restrict__ bias,
    unsigned short* __restrict__ out) {
  constexpr int NCI    = CIN / 32;
  constexpr int LOGNCI = (NCI == 16) ? 4 : 3;
  constexpr int NT     = 3 * NCI;
  constexpr int GPR    = CIN / 8;                 // granules per (y) row
  constexpr int PXS    = 136;                     // staged px per q-row
  constexpr int A_BYTES = 8 * PXS * 16;           // 17 408
  constexpr int B_BYTES = 12 * 256 * 16;          // 49 152
  constexpr int BUF     = A_BYTES + B_BYTES;      // 66 560
  __shared__ __align__(16) unsigned char smem[2 * BUF];

  const int tid  = threadIdx.x;
  const int wave = tid >> 6, lane = tid & 63;
  const int l31 = lane & 31, hi = lane >> 5;
  const int wm = wave >> 2, wn = wave & 3;        // 2M x 4N wave grid
  const int b = blockIdx.x >> 6;
  const int y0 = (blockIdx.x & 63) * 2;
  const int brow = b * 130 + y0;                  // input row at dy=0

  // ---- per-thread A staging decode (17 instrs, wave-strided s=wave+8i) ----
  // chunk c -> (rw = c/544, q = (c/136)&3, px = c%136); LDS dest = c*16;
  // source rel (shorts) = (rw*GPR + q)*1040 + px*8   (1040 = 130*8)
  int a_rel[3], a_c[3];
#pragma unroll
  for (int i = 0; i < 3; ++i) {
    int s = wave + i * 8;
    if (s < 17) {
      int c = s * 64 + lane;
      int px = c % PXS, t2 = c / PXS;
      int q = t2 & 3, rw = t2 >> 2;
      a_rel[i] = (rw * GPR + q) * 1040 + px * 8;
      a_c[i] = c * 16;
    } else { a_rel[i] = 0; a_c[i] = 0; }
  }

  // bias loads issued (and retired) before the pipeline's vmcnt counting
  const float bb0 = bias[wn * 64 + l31];
  const float bb1 = bias[wn * 64 + 32 + l31];

  f32x16 acc[4][2] = {};

  auto stage = [&](int tile) {
    const int dy = tile >> LOGNCI;
    const int kt = tile & (NCI - 1);
    unsigned char* sb = smem + (size_t)(tile & 1) * BUF;
    const unsigned short* Ab = Ap + ((size_t)(brow + dy) * GPR + kt * 4) * 1040;
    GLOAD_LDS16(Ab + a_rel[0], sb + a_c[0]);
    GLOAD_LDS16(Ab + a_rel[1], sb + a_c[1]);
    if (wave == 0) GLOAD_LDS16(Ab + a_rel[2], sb + a_c[2]);
    const unsigned short* Bb = WTp + (size_t)(dy * NCI + kt) * 24576;
#pragma unroll
    for (int i = 0; i < 6; ++i) {
      int c = (wave * 6 + i) * 64 + lane;
      GLOAD_LDS16(Bb + (size_t)c * 8, sb + A_BYTES + c * 16);
    }
  };

  // prologue: stage tile 0, publish
  stage(0);
  asm volatile("s_waitcnt vmcnt(0)" ::: "memory");
  __builtin_amdgcn_s_barrier();

#pragma unroll 2
  for (int t = 0; t < NT; ++t) {
    const unsigned char* sb = smem + (size_t)(t & 1) * BUF;
#pragma unroll
    for (int dx = 0; dx < 3; ++dx) {
      // ---- this phase's fragment reads (buf t; conflict-free contiguous) --
      bf16x8 af[2][4], bfr[2][2];
#pragma unroll
      for (int ks = 0; ks < 2; ++ks) {
        const int q_ = ks * 2 + hi;
        const int ab = ((wm * 4 + q_) * PXS + dx + l31) * 16;
        const int bb = A_BYTES + ((dx * 4 + q_) * 256 + wn * 64 + l31) * 16;
#pragma unroll
        for (int i = 0; i < 4; ++i)
          af[ks][i] = *(const bf16x8*)(sb + ab + i * 512);
#pragma unroll
        for (int j = 0; j < 2; ++j)
          bfr[ks][j] = *(const bf16x8*)(sb + bb + j * 512);
      }
      // ---- staging schedule for tile t+1 ----------------------------------
      if (dx == 0 && t + 1 < NT) stage(t + 1);     // DMAs -> buf^1 (WAR-safe)
      if (dx == 2 && t + 1 < NT)                   // issued 2 phases ago: no stall
        asm volatile("s_waitcnt vmcnt(0)" ::: "memory");
      __builtin_amdgcn_sched_barrier(0);
      __builtin_amdgcn_s_barrier();                // (t,2): publishes buf t+1
      asm volatile("s_waitcnt lgkmcnt(0)" ::: "memory");
      __builtin_amdgcn_sched_barrier(0);
      __builtin_amdgcn_s_setprio(1);
#pragma unroll
      for (int ks = 0; ks < 2; ++ks)
#pragma unroll
        for (int i = 0; i < 4; ++i)
#pragma unroll
          for (int j = 0; j < 2; ++j)
            acc[i][j] = __builtin_amdgcn_mfma_f32_32x32x16_bf16(
                af[ks][i], bfr[ks][j], acc[i][j], 0, 0, 0);
      __builtin_amdgcn_s_setprio(0);
      __builtin_amdgcn_sched_barrier(0);
      __builtin_amdgcn_s_barrier();                // phase close
    }
  }

  // epilogue: 32x32 C/D layout: col = lane&31, row = (reg&3)+8*(reg>>2)+4*hi
#pragma unroll
  for (int i = 0; i < 4; ++i) {
#pragma unroll
    for (int j = 0; j < 2; ++j) {
      const int n = wn * 64 + j * 32 + l31;
      const float bb = j ? bb1 : bb0;
#pragma unroll
      for (int reg = 0; reg < 16; ++reg) {
        int px = i * 32 + (reg & 3) + 8 * (reg >> 2) + 4 * hi;
        float v = fmaxf(acc[i][j][reg] + bb, 0.f);
        size_t off;
        if (MODE == 0)    // h1_pad granule-major [b][y][32 g][130 px][8]
          off = (((size_t)(brow + wm + 1) * 32 + (n >> 3)) * 130 + (px + 1)) * 8 + (n & 7);
        else              // h2 flat NHWC [pix][256]
          off = ((size_t)((b * 128 + y0 + wm) * 128) + px) * 256 + n;
        out[off] = f2bf(v);
      }
    }
  }
}

// ---- heads: h2[65536][256] x WhT[54(pad 64)][256] + bias, softmax pairs ----
__global__ __launch_bounds__(256) void heads_kernel(
    const unsigned short* __restrict__ h2,
    const unsigned short* __restrict__ WhT,
    const float* __restrict__ br, const float* __restrict__ bc,
    float* __restrict__ out) {
  __shared__ __align__(16) unsigned short As[64][264];
  const int tid = threadIdx.x;
  const int wave = tid >> 6, lane = tid & 63;
  const int quad = lane >> 4, l16 = lane & 15;
  const int pix0 = blockIdx.x * 64;
#pragma unroll
  for (int r = 0; r < 8; ++r) {
    int s = r * 256 + tid;
    int row = s >> 5, seg = s & 31;                  // 64 rows x 32 x 16B
    *(uint4*)&As[row][seg * 8] =
        *(const uint4*)(h2 + (size_t)(pix0 + row) * 256 + seg * 8);
  }
  __syncthreads();
  f32x4 acc[4] = {};
#pragma unroll
  for (int ks = 0; ks < 8; ++ks) {
    bf16x8 af = *(const bf16x8*)&As[wave * 16 + l16][ks * 32 + quad * 8];
#pragma unroll
    for (int j = 0; j < 4; ++j) {
      bf16x8 bfr = *(const bf16x8*)(WhT + (size_t)(j * 16 + l16) * 256 + ks * 32 + quad * 8);
      acc[j] = __builtin_amdgcn_mfma_f32_16x16x32_bf16(af, bfr, acc[j], 0, 0, 0);
    }
  }
#pragma unroll
  for (int j = 0; j < 4; ++j) {
    int n = j * 16 + l16;                            // head channel (cls 0-17, reg 18-53)
    float bias = 0.f;
    if (n < 18) bias = bc[n];
    else if (n < 54) bias = br[n - 18];
#pragma unroll
    for (int r = 0; r < 4; ++r) {
      int p = pix0 + wave * 16 + quad * 4 + r;       // pixel
      float v = acc[j][r] + bias;
      float partner = __shfl_xor(v, 1);              // cls pair (even,odd lanes)
      if (n < 18) {
        float mx = fmaxf(v, partner);
        float e0 = __expf(v - mx), e1 = __expf(partner - mx);
        int a = n >> 1, sl = n & 1;
        out[(size_t)p * 54 + a * 6 + sl] = e0 / (e0 + e1);
      } else if (n < 54) {
        int rr = n - 18, a = rr >> 2, sl = (rr & 3) + 2;
        out[(size_t)p * 54 + a * 6 + sl] = v;
      }
    }
  }
}

// ---------------------------------------------------------------------------
extern "C" void kernel_launch(void* const* d_in, const int* in_sizes, int n_in,
                              void* d_out, int out_size, void* d_ws, size_t ws_size,
                              hipStream_t stream) {
  const float* x  = (const float*)d_in[0];
  const float* W1 = (const float*)d_in[1];
  const float* b1 = (const float*)d_in[2];
  const float* W2 = (const float*)d_in[3];
  const float* b2 = (const float*)d_in[4];
  const float* Wr = (const float*)d_in[5];
  const float* br = (const float*)d_in[6];
  const float* Wc = (const float*)d_in[7];
  const float* bc = (const float*)d_in[8];
  float* out = (float*)d_out;

  // workspace carve-up (bytes).  NOTE: conv3x3 A-staging over-reads up to
  // ~1 KB past x_pad / h1_pad row ends (136-px q-rows vs 130 stored); those
  // reads land in the NEXT buffer and are never consumed by MFMA.
  constexpr size_t XPAD_B  = 4ull * 130 * 130 * 512 * 2;   //  69,222,400
  constexpr size_t H1PAD_B = 4ull * 130 * 130 * 256 * 2;   //  34,611,200
  constexpr size_t H2_B    = 4ull * 128 * 128 * 256 * 2;   //  33,554,432
  constexpr size_t W1T_B   = 9ull * 256 * 512 * 2;         //   2,359,296
  constexpr size_t W2T_B   = 9ull * 256 * 256 * 2;         //   1,179,648
  char* ws = (char*)d_ws;
  unsigned short* x_pad  = (unsigned short*)(ws);
  unsigned short* h1_pad = (unsigned short*)(ws + XPAD_B);
  unsigned short* h2     = (unsigned short*)(ws + XPAD_B + H1PAD_B);
  unsigned short* W1T    = (unsigned short*)(ws + XPAD_B + H1PAD_B + H2_B);
  unsigned short* W2T    = (unsigned short*)(ws + XPAD_B + H1PAD_B + H2_B + W1T_B);
  unsigned short* WhT    = (unsigned short*)(ws + XPAD_B + H1PAD_B + H2_B + W1T_B + W2T_B);

  // zero the padded head-weight block (rows 54..63 are read by MFMA)
  hipMemsetAsync(WhT, 0, 64ull * 256 * 2, stream);
  // weight repacks: conv weights -> per-tile packed order; heads -> B^T
  pack_w<<<576, 256, 0, stream>>>(W1, W1T, 512);
  pack_w<<<288, 256, 0, stream>>>(W2, W2T, 256);
  transpose_cvt<<<dim3(8, 1, 1),  dim3(32, 8), 0, stream>>>(Wc, WhT, 256, 18);
  transpose_cvt<<<dim3(8, 2, 1),  dim3(32, 8), 0, stream>>>(Wr, WhT + 18 * 256, 256, 36);
  // input pad+convert (granule-major), h1 halo zero
  convert_x<<<16900, 256, 0, stream>>>(x, x_pad);
  zero_h1_borders<<<8450, 256, 0, stream>>>(h1_pad);
  // conv1: 512ci -> h1_pad (granule-major) ; conv2: 256ci -> h2 flat
  conv3x3<512, 0><<<256, 512, 0, stream>>>(x_pad, W1T, b1, h1_pad);
  conv3x3<256, 1><<<256, 512, 0, stream>>>(h1_pad, W2T, b2, h2);
  // 1x1 heads + softmax + interleave
  heads_kernel<<<1024, 256, 0, stream>>>(h2, WhT, br, bc, out);
}